// Round 4
// baseline (130.479 us; speedup 1.0000x reference)
//
#include <hip/hip_runtime.h>

#define NN   10000
#define NE   640000
#define DIM  128
#define NREP 8
#define ROWS_PAD 10240

typedef __attribute__((ext_vector_type(8))) short bf16x8;
typedef __attribute__((ext_vector_type(4))) float f32x4;

__device__ inline unsigned short f2bf(float f) {
    unsigned u = __builtin_bit_cast(unsigned, f);
    unsigned r = (u + 0x7fffu + ((u >> 16) & 1u)) >> 16;
    return (unsigned short)r;
}

// ===========================================================================
// PRIMARY ws layout (bytes), total 5,226,496:
//   deg8/repoff [8][10240] int @ 0         (327,680)  } overlaid by aggb
//   rank  uchar[640000]       @ 327,680    (640,000)  } (2.56 MB) at gather
//   (free to 2,560,000 — rest of aggb)                } time (dead by then)
//   rowptr int[10240]         @ 2,560,000  (40,960)
//   colidx int[640000]        @ 2,600,960  (2,560,000)
//   W1p ushort[16384]         @ 5,160,960  (32,768)   bf16 MFMA-frag order
//   W2p ushort[16384]         @ 5,193,728  (32,768)
// ===========================================================================
#define OFF_RANK   327680
#define OFF_ROWPTR 2560000
#define OFF_COLIDX 2600960
#define OFF_W1P    5160960
#define OFF_W2P    5193728
#define WS_NEED    5226496

// --- pack W1/W2 into MFMA B-frag order (bf16) + zero deg8 -------------------
// B-frag for mfma_f32_16x16x32_bf16: lane l, elem e holds
// B[kt*32 + (l>>4)*8 + e][nt*16 + (l&15)]; frags stored 16B-contiguous.
__global__ void pack_zero_kernel(const float* __restrict__ W1,
                                 const float* __restrict__ W2,
                                 unsigned short* __restrict__ W1p,
                                 unsigned short* __restrict__ W2p,
                                 int* __restrict__ deg8) {
    int id = blockIdx.x * 256 + threadIdx.x;
    if (id < 32768) {
        const float* W = (id < 16384) ? W1 : W2;
        unsigned short* Wp = (id < 16384) ? W1p : W2p;
        int f = id & 16383;
        int e = f & 7, lane = (f >> 3) & 63, kt = (f >> 9) & 3, nt = f >> 11;
        int kglob = kt * 32 + (lane >> 4) * 8 + e;
        int jglob = nt * 16 + (lane & 15);
        Wp[f] = f2bf(W[kglob * DIM + jglob]);
    } else {
        int z = id - 32768;
        if (z < NREP * ROWS_PAD) deg8[z] = 0;
    }
}

// --- count with 8-way replicated counters; rank = within-(rep,row) order ----
// rep = blockIdx.x & 7 is a pure function of e, recomputed in fill.
__global__ void count_rank_kernel(const int* __restrict__ ei,
                                  int* __restrict__ deg8,
                                  unsigned char* __restrict__ rank) {
    int e = blockIdx.x * 256 + threadIdx.x;
    if (e < NE) {
        int r = ei[2 * e];
        int rep = blockIdx.x & (NREP - 1);
        rank[e] = (unsigned char)atomicAdd(&deg8[rep * ROWS_PAD + r], 1);
    }
}

// --- single-block scan: rowptr + in-place deg8 -> repoff --------------------
// Thread t owns rows [t*10, t*10+10): reads its own deg8 cells in both
// phases and overwrites them with repoff (no cross-thread hazard on deg8).
__global__ __launch_bounds__(1024) void scan_kernel(int* __restrict__ deg8,
                                                    int* __restrict__ rowptr) {
    __shared__ int wtot[16];
    const int t = threadIdx.x;
    const int base = t * 10;
    int local[10];
    int s = 0;
    #pragma unroll
    for (int i = 0; i < 10; ++i) {
        int row = base + i;
        int d = 0;
        if (row < NN) {
            #pragma unroll
            for (int rp = 0; rp < NREP; ++rp) d += deg8[rp * ROWS_PAD + row];
        }
        local[i] = s;
        s += d;
    }
    const int mySum = s;
    #pragma unroll
    for (int off = 1; off < 64; off <<= 1) {
        int v = __shfl_up(s, (unsigned)off, 64);
        if ((t & 63) >= off) s += v;
    }
    if ((t & 63) == 63) wtot[t >> 6] = s;
    __syncthreads();
    if (t == 0) {
        int run = 0;
        #pragma unroll
        for (int i = 0; i < 16; ++i) { int v = wtot[i]; wtot[i] = run; run += v; }
    }
    __syncthreads();
    const int ex = wtot[t >> 6] + (s - mySum);
    #pragma unroll
    for (int i = 0; i < 10; ++i) {
        int row = base + i;
        if (row < NN) {
            int run = ex + local[i];
            rowptr[row] = run;
            #pragma unroll
            for (int rp = 0; rp < NREP; ++rp) {
                int d = deg8[rp * ROWS_PAD + row];
                deg8[rp * ROWS_PAD + row] = run;   // repoff[rp][row]
                run += d;
            }
        }
    }
    if (t == 1023) rowptr[NN] = ex + mySum;
}

// --- fill CSR columns: atomic-free ------------------------------------------
__global__ void fill_rank_kernel(const int* __restrict__ ei,
                                 const unsigned char* __restrict__ rank,
                                 const int* __restrict__ repoff,
                                 int* __restrict__ colidx) {
    int e = blockIdx.x * 256 + threadIdx.x;
    if (e < NE) {
        int r = ei[2 * e];
        int c = ei[2 * e + 1];
        int rep = blockIdx.x & (NREP - 1);
        colidx[repoff[rep * ROWS_PAD + r] + (int)rank[e]] = c;
    }
}

// --- gather: agg_bf16[n,:] = bf16(x[n,:] + sum_neighbors x[c,:]) ------------
__global__ __launch_bounds__(256) void gather_bf16_kernel(
        const float* __restrict__ x,
        const int* __restrict__ rowptr,
        const int* __restrict__ colidx,
        unsigned short* __restrict__ aggb) {
    const int node = blockIdx.x * 8 + (threadIdx.x >> 5);
    const int sub  = threadIdx.x & 31;
    if (node >= NN) return;
    const int s = rowptr[node];
    const int e = rowptr[node + 1];

    float4 acc = *(reinterpret_cast<const float4*>(x + (size_t)node * DIM) + sub);
    float4 a1 = {0.f, 0.f, 0.f, 0.f}, a2 = {0.f, 0.f, 0.f, 0.f}, a3 = {0.f, 0.f, 0.f, 0.f};

    int k = s;
    for (; (k & 3) != 0 && k < e; ++k) {
        float4 v = *(reinterpret_cast<const float4*>(x + (size_t)colidx[k] * DIM) + sub);
        acc.x += v.x; acc.y += v.y; acc.z += v.z; acc.w += v.w;
    }
    for (; k + 4 <= e; k += 4) {
        int4 c = *reinterpret_cast<const int4*>(colidx + k);
        float4 v0 = *(reinterpret_cast<const float4*>(x + (size_t)c.x * DIM) + sub);
        float4 v1 = *(reinterpret_cast<const float4*>(x + (size_t)c.y * DIM) + sub);
        float4 v2 = *(reinterpret_cast<const float4*>(x + (size_t)c.z * DIM) + sub);
        float4 v3 = *(reinterpret_cast<const float4*>(x + (size_t)c.w * DIM) + sub);
        acc.x += v0.x; acc.y += v0.y; acc.z += v0.z; acc.w += v0.w;
        a1.x += v1.x; a1.y += v1.y; a1.z += v1.z; a1.w += v1.w;
        a2.x += v2.x; a2.y += v2.y; a2.z += v2.z; a2.w += v2.w;
        a3.x += v3.x; a3.y += v3.y; a3.z += v3.z; a3.w += v3.w;
    }
    for (; k < e; ++k) {
        float4 v = *(reinterpret_cast<const float4*>(x + (size_t)colidx[k] * DIM) + sub);
        acc.x += v.x; acc.y += v.y; acc.z += v.z; acc.w += v.w;
    }
    acc.x += (a1.x + a2.x) + a3.x;
    acc.y += (a1.y + a2.y) + a3.y;
    acc.z += (a1.z + a2.z) + a3.z;
    acc.w += (a1.w + a2.w) + a3.w;

    ushort4 pk;
    pk.x = f2bf(acc.x); pk.y = f2bf(acc.y); pk.z = f2bf(acc.z); pk.w = f2bf(acc.w);
    *reinterpret_cast<ushort4*>(aggb + (size_t)node * DIM + sub * 4) = pk;
}

// --- fused 2-layer MLP on MFMA ----------------------------------------------
__global__ __launch_bounds__(256) void mlp_mfma_kernel(
        const unsigned short* __restrict__ aggb,
        const unsigned short* __restrict__ W1p,
        const unsigned short* __restrict__ W2p,
        const float* __restrict__ b1,
        const float* __restrict__ b2,
        float* __restrict__ out) {
    __shared__ __align__(16) unsigned short hbuf[4][16][136];

    const int wid  = threadIdx.x >> 6;
    const int lane = threadIdx.x & 63;
    const int t = blockIdx.x * 4 + wid;
    if (t >= NN / 16) return;            // 625 tiles
    const int row0 = t * 16;
    const int r16  = lane & 15;
    const int kg   = lane >> 4;
    const int drow = kg * 4;

    bf16x8 af[4];
    #pragma unroll
    for (int kt = 0; kt < 4; ++kt)
        af[kt] = *reinterpret_cast<const bf16x8*>(
            aggb + (size_t)(row0 + r16) * DIM + kt * 32 + kg * 8);

    const f32x4 zero = {0.f, 0.f, 0.f, 0.f};
    f32x4 acc[8];
    #pragma unroll
    for (int nt = 0; nt < 8; ++nt) acc[nt] = zero;

    #pragma unroll
    for (int kt = 0; kt < 4; ++kt) {
        #pragma unroll
        for (int nt = 0; nt < 8; ++nt) {
            bf16x8 w = *reinterpret_cast<const bf16x8*>(
                W1p + ((nt * 4 + kt) * 64 + lane) * 8);
            acc[nt] = __builtin_amdgcn_mfma_f32_16x16x32_bf16(af[kt], w, acc[nt], 0, 0, 0);
        }
    }

    #pragma unroll
    for (int nt = 0; nt < 8; ++nt) {
        float bv = b1[nt * 16 + r16];
        #pragma unroll
        for (int r = 0; r < 4; ++r) {
            float h = fmaxf(acc[nt][r] + bv, 0.0f);
            hbuf[wid][drow + r][nt * 16 + r16] = f2bf(h);
        }
    }

    bf16x8 hf[4];
    #pragma unroll
    for (int kt = 0; kt < 4; ++kt)
        hf[kt] = *reinterpret_cast<const bf16x8*>(&hbuf[wid][r16][kt * 32 + kg * 8]);

    f32x4 acc2[8];
    #pragma unroll
    for (int nt = 0; nt < 8; ++nt) acc2[nt] = zero;

    #pragma unroll
    for (int kt = 0; kt < 4; ++kt) {
        #pragma unroll
        for (int nt = 0; nt < 8; ++nt) {
            bf16x8 w = *reinterpret_cast<const bf16x8*>(
                W2p + ((nt * 4 + kt) * 64 + lane) * 8);
            acc2[nt] = __builtin_amdgcn_mfma_f32_16x16x32_bf16(hf[kt], w, acc2[nt], 0, 0, 0);
        }
    }

    #pragma unroll
    for (int nt = 0; nt < 8; ++nt) {
        float bv = b2[nt * 16 + r16];
        #pragma unroll
        for (int r = 0; r < 4; ++r)
            out[(size_t)(row0 + drow + r) * DIM + nt * 16 + r16] = acc2[nt][r] + bv;
    }
}

// ===========================================================================
// FALLBACK PATH (round-2 proven kernels; ws >= 2,682,880 B)
// ===========================================================================
__global__ void fb_zero_kernel(int* __restrict__ p, int n) {
    int i = blockIdx.x * blockDim.x + threadIdx.x;
    if (i < n) p[i] = 0;
}
__global__ void fb_count_kernel(const int* __restrict__ ei, int* __restrict__ deg) {
    int e = blockIdx.x * blockDim.x + threadIdx.x;
    if (e < NE) atomicAdd(&deg[ei[2 * e]], 1);
}
__global__ __launch_bounds__(1024) void fb_scan_kernel(const int* __restrict__ deg,
                                                       int* __restrict__ rowptr) {
    __shared__ int wtot[16];
    const int t = threadIdx.x;
    const int base = t * 10;
    int local[10];
    int s = 0;
    #pragma unroll
    for (int i = 0; i < 10; ++i) {
        int v = (base + i < NN) ? deg[base + i] : 0;
        local[i] = s;
        s += v;
    }
    const int mySum = s;
    #pragma unroll
    for (int off = 1; off < 64; off <<= 1) {
        int v = __shfl_up(s, (unsigned)off, 64);
        if ((t & 63) >= off) s += v;
    }
    if ((t & 63) == 63) wtot[t >> 6] = s;
    __syncthreads();
    if (t == 0) {
        int run = 0;
        #pragma unroll
        for (int i = 0; i < 16; ++i) { int v = wtot[i]; wtot[i] = run; run += v; }
    }
    __syncthreads();
    const int ex = wtot[t >> 6] + (s - mySum);
    #pragma unroll
    for (int i = 0; i < 10; ++i)
        if (base + i < NN) rowptr[base + i] = ex + local[i];
    if (t == 1023) rowptr[NN] = ex + mySum;
}
__global__ void fb_fill_kernel(const int* __restrict__ ei, const int* __restrict__ rowptr,
                               int* __restrict__ fill, int* __restrict__ colidx) {
    int e = blockIdx.x * blockDim.x + threadIdx.x;
    if (e < NE) {
        int r = ei[2 * e], c = ei[2 * e + 1];
        colidx[rowptr[r] + atomicAdd(&fill[r], 1)] = c;
    }
}
__global__ __launch_bounds__(128) void fb_gather_kernel(const float* __restrict__ x,
                                                        const int* __restrict__ rowptr,
                                                        const int* __restrict__ colidx,
                                                        float* __restrict__ agg) {
    const int n = blockIdx.x, j = threadIdx.x;
    const int s = rowptr[n], e = rowptr[n + 1];
    float acc = x[(size_t)n * DIM + j];
    float a0 = 0.f, a1 = 0.f, a2 = 0.f, a3 = 0.f;
    int k = s;
    for (; k + 4 <= e; k += 4) {
        a0 += x[(size_t)colidx[k + 0] * DIM + j];
        a1 += x[(size_t)colidx[k + 1] * DIM + j];
        a2 += x[(size_t)colidx[k + 2] * DIM + j];
        a3 += x[(size_t)colidx[k + 3] * DIM + j];
    }
    for (; k < e; ++k) acc += x[(size_t)colidx[k] * DIM + j];
    agg[(size_t)n * DIM + j] = acc + (a0 + a1) + (a2 + a3);
}
__global__ __launch_bounds__(512) void fb_mlp_kernel(
        const float* __restrict__ agg,
        const float* __restrict__ W1, const float* __restrict__ b1,
        const float* __restrict__ W2, const float* __restrict__ b2,
        float* __restrict__ out) {
    __shared__ float w1s[DIM * DIM];
    __shared__ float w2s[DIM * DIM];
    __shared__ float b1s[DIM], b2s[DIM];
    __shared__ float as[4][DIM], hs[4][DIM];
    for (int i = threadIdx.x; i < DIM * DIM; i += blockDim.x) { w1s[i] = W1[i]; w2s[i] = W2[i]; }
    if (threadIdx.x < DIM) { b1s[threadIdx.x] = b1[threadIdx.x]; b2s[threadIdx.x] = b2[threadIdx.x]; }
    __syncthreads();
    const int r = threadIdx.x >> 7, j = threadIdx.x & 127;
    for (int base = blockIdx.x * 4; base < NN; base += gridDim.x * 4) {
        int rowid = base + r;
        as[r][j] = (rowid < NN) ? agg[(size_t)rowid * DIM + j] : 0.0f;
        __syncthreads();
        float acc = b1s[j];
        #pragma unroll 8
        for (int k = 0; k < DIM; ++k) acc = fmaf(as[r][k], w1s[k * DIM + j], acc);
        hs[r][j] = fmaxf(acc, 0.0f);
        __syncthreads();
        float acc2 = b2s[j];
        #pragma unroll 8
        for (int k = 0; k < DIM; ++k) acc2 = fmaf(hs[r][k], w2s[k * DIM + j], acc2);
        if (rowid < NN) out[(size_t)rowid * DIM + j] = acc2;
        __syncthreads();
    }
}

// ===========================================================================
extern "C" void kernel_launch(void* const* d_in, const int* in_sizes, int n_in,
                              void* d_out, int out_size, void* d_ws, size_t ws_size,
                              hipStream_t stream) {
    const float* x  = (const float*)d_in[0];
    const int*   ei = (const int*)d_in[1];
    const float* W1 = (const float*)d_in[2];
    const float* b1 = (const float*)d_in[3];
    const float* W2 = (const float*)d_in[4];
    const float* b2 = (const float*)d_in[5];
    float* out = (float*)d_out;

    if (ws_size >= WS_NEED) {
        char* ws = (char*)d_ws;
        int* deg8 = (int*)ws;                                  // -> repoff after scan
        unsigned char* rank = (unsigned char*)(ws + OFF_RANK);
        unsigned short* aggb = (unsigned short*)ws;            // overlays deg8+rank
        int* rowptr = (int*)(ws + OFF_ROWPTR);
        int* colidx = (int*)(ws + OFF_COLIDX);
        unsigned short* W1p = (unsigned short*)(ws + OFF_W1P);
        unsigned short* W2p = (unsigned short*)(ws + OFF_W2P);

        pack_zero_kernel<<<(32768 + NREP * ROWS_PAD + 255) / 256, 256, 0, stream>>>(
            W1, W2, W1p, W2p, deg8);
        count_rank_kernel<<<(NE + 255) / 256, 256, 0, stream>>>(ei, deg8, rank);
        scan_kernel<<<1, 1024, 0, stream>>>(deg8, rowptr);
        fill_rank_kernel<<<(NE + 255) / 256, 256, 0, stream>>>(ei, rank, deg8, colidx);
        gather_bf16_kernel<<<NN / 8, 256, 0, stream>>>(x, rowptr, colidx, aggb);
        mlp_mfma_kernel<<<(NN / 16 + 3) / 4, 256, 0, stream>>>(aggb, W1p, W2p, b1, b2, out);
    } else {
        int* wsI    = (int*)d_ws;
        int* deg    = wsI;
        int* fillc  = wsI + 10240;
        int* rowptr = wsI + 20480;
        int* colidx = wsI + 30720;
        const size_t csr_bytes = (size_t)(30720 + NE) * sizeof(int);
        const size_t agg_bytes = (size_t)NN * DIM * sizeof(float);
        float* agg = (ws_size >= csr_bytes + agg_bytes)
                         ? (float*)((char*)d_ws + csr_bytes) : out;

        fb_zero_kernel<<<(20480 + 255) / 256, 256, 0, stream>>>(deg, 20480);
        fb_count_kernel<<<(NE + 255) / 256, 256, 0, stream>>>(ei, deg);
        fb_scan_kernel<<<1, 1024, 0, stream>>>(deg, rowptr);
        fb_fill_kernel<<<(NE + 255) / 256, 256, 0, stream>>>(ei, rowptr, fillc, colidx);
        fb_gather_kernel<<<NN, 128, 0, stream>>>(x, rowptr, colidx, agg);
        fb_mlp_kernel<<<256, 512, 0, stream>>>(agg, W1, b1, W2, b2, out);
    }
}

// Round 5
// 81.442 us; speedup vs baseline: 1.6021x; 1.6021x over previous
//
#include <hip/hip_runtime.h>

#define NN   10000
#define NE   640000
#define DIM  128
#define NREP 8
#define ROWS_PAD 10240

typedef __attribute__((ext_vector_type(8))) short bf16x8;
typedef __attribute__((ext_vector_type(4))) float f32x4;

__device__ inline unsigned short f2bf(float f) {
    unsigned u = __builtin_bit_cast(unsigned, f);
    unsigned r = (u + 0x7fffu + ((u >> 16) & 1u)) >> 16;
    return (unsigned short)r;
}

// ===========================================================================
// PRIMARY ws layout (bytes), total 5,226,496:
//   deg8/repoff [8][10240] int @ 0         (327,680)  } all overlaid by aggb
//   rank  uchar[640000]       @ 327,680    (640,000)  } (2.56 MB) at gather
//   deg   int[10240]          @ 967,680    (40,960)   } time (dead by then)
//   rowptr int[10240]         @ 2,560,000  (40,960)
//   colidx int[640000]        @ 2,600,960  (2,560,000)
//   W1p ushort[16384]         @ 5,160,960  (32,768)   bf16 MFMA-frag order
//   W2p ushort[16384]         @ 5,193,728  (32,768)
// ===========================================================================
#define OFF_RANK   327680
#define OFF_DEG    967680
#define OFF_ROWPTR 2560000
#define OFF_COLIDX 2600960
#define OFF_W1P    5160960
#define OFF_W2P    5193728
#define WS_NEED    5226496

// --- pack W1/W2 into MFMA B-frag order (bf16) + zero deg8 -------------------
__global__ void pack_zero_kernel(const float* __restrict__ W1,
                                 const float* __restrict__ W2,
                                 unsigned short* __restrict__ W1p,
                                 unsigned short* __restrict__ W2p,
                                 int* __restrict__ deg8) {
    int id = blockIdx.x * 256 + threadIdx.x;
    if (id < 32768) {
        const float* W = (id < 16384) ? W1 : W2;
        unsigned short* Wp = (id < 16384) ? W1p : W2p;
        int f = id & 16383;
        int e = f & 7, lane = (f >> 3) & 63, kt = (f >> 9) & 3, nt = f >> 11;
        int kglob = kt * 32 + (lane >> 4) * 8 + e;
        int jglob = nt * 16 + (lane & 15);
        Wp[f] = f2bf(W[kglob * DIM + jglob]);
    } else {
        int z = id - 32768;
        if (z < NREP * ROWS_PAD) deg8[z] = 0;
    }
}

// --- count with 8-way replicated counters; rank = within-(rep,row) order ----
__global__ void count_rank_kernel(const int* __restrict__ ei,
                                  int* __restrict__ deg8,
                                  unsigned char* __restrict__ rank) {
    int e = blockIdx.x * 256 + threadIdx.x;
    if (e < NE) {
        int r = ei[2 * e];
        int rep = blockIdx.x & (NREP - 1);
        rank[e] = (unsigned char)atomicAdd(&deg8[rep * ROWS_PAD + r], 1);
    }
}

// --- grid-parallel: deg[row] = sum over replicas ----------------------------
__global__ void reduce_deg_kernel(const int* __restrict__ deg8,
                                  int* __restrict__ deg) {
    int row = blockIdx.x * 256 + threadIdx.x;
    if (row < NN) {
        int d = 0;
        #pragma unroll
        for (int rp = 0; rp < NREP; ++rp) d += deg8[rp * ROWS_PAD + row];
        deg[row] = d;
    }
}

// --- single-block exclusive scan over deg (round-3 proven, 40 KB) -----------
__global__ __launch_bounds__(1024) void scan_kernel(const int* __restrict__ deg,
                                                    int* __restrict__ rowptr) {
    __shared__ int wtot[16];
    const int t = threadIdx.x;
    const int base = t * 10;
    int local[10];
    int s = 0;
    #pragma unroll
    for (int i = 0; i < 10; ++i) {
        int v = (base + i < NN) ? deg[base + i] : 0;
        local[i] = s;
        s += v;
    }
    const int mySum = s;
    #pragma unroll
    for (int off = 1; off < 64; off <<= 1) {
        int v = __shfl_up(s, (unsigned)off, 64);
        if ((t & 63) >= off) s += v;
    }
    if ((t & 63) == 63) wtot[t >> 6] = s;
    __syncthreads();
    if (t == 0) {
        int run = 0;
        #pragma unroll
        for (int i = 0; i < 16; ++i) { int v = wtot[i]; wtot[i] = run; run += v; }
    }
    __syncthreads();
    const int ex = wtot[t >> 6] + (s - mySum);
    #pragma unroll
    for (int i = 0; i < 10; ++i)
        if (base + i < NN) rowptr[base + i] = ex + local[i];
    if (t == 1023) rowptr[NN] = ex + mySum;
}

// --- grid-parallel: deg8 -> repoff (in place), per row over 8 replicas ------
__global__ void repoff_kernel(int* __restrict__ deg8,
                              const int* __restrict__ rowptr) {
    int row = blockIdx.x * 256 + threadIdx.x;
    if (row < NN) {
        int run = rowptr[row];
        #pragma unroll
        for (int rp = 0; rp < NREP; ++rp) {
            int d = deg8[rp * ROWS_PAD + row];
            deg8[rp * ROWS_PAD + row] = run;
            run += d;
        }
    }
}

// --- fill CSR columns: atomic-free ------------------------------------------
__global__ void fill_rank_kernel(const int* __restrict__ ei,
                                 const unsigned char* __restrict__ rank,
                                 const int* __restrict__ repoff,
                                 int* __restrict__ colidx) {
    int e = blockIdx.x * 256 + threadIdx.x;
    if (e < NE) {
        int r = ei[2 * e];
        int c = ei[2 * e + 1];
        int rep = blockIdx.x & (NREP - 1);
        colidx[repoff[rep * ROWS_PAD + r] + (int)rank[e]] = c;
    }
}

// --- gather: agg_bf16[n,:] = bf16(x[n,:] + sum_neighbors x[c,:]) ------------
__global__ __launch_bounds__(256) void gather_bf16_kernel(
        const float* __restrict__ x,
        const int* __restrict__ rowptr,
        const int* __restrict__ colidx,
        unsigned short* __restrict__ aggb) {
    const int node = blockIdx.x * 8 + (threadIdx.x >> 5);
    const int sub  = threadIdx.x & 31;
    if (node >= NN) return;
    const int s = rowptr[node];
    const int e = rowptr[node + 1];

    float4 acc = *(reinterpret_cast<const float4*>(x + (size_t)node * DIM) + sub);
    float4 a1 = {0.f, 0.f, 0.f, 0.f}, a2 = {0.f, 0.f, 0.f, 0.f}, a3 = {0.f, 0.f, 0.f, 0.f};

    int k = s;
    for (; (k & 3) != 0 && k < e; ++k) {
        float4 v = *(reinterpret_cast<const float4*>(x + (size_t)colidx[k] * DIM) + sub);
        acc.x += v.x; acc.y += v.y; acc.z += v.z; acc.w += v.w;
    }
    for (; k + 4 <= e; k += 4) {
        int4 c = *reinterpret_cast<const int4*>(colidx + k);
        float4 v0 = *(reinterpret_cast<const float4*>(x + (size_t)c.x * DIM) + sub);
        float4 v1 = *(reinterpret_cast<const float4*>(x + (size_t)c.y * DIM) + sub);
        float4 v2 = *(reinterpret_cast<const float4*>(x + (size_t)c.z * DIM) + sub);
        float4 v3 = *(reinterpret_cast<const float4*>(x + (size_t)c.w * DIM) + sub);
        acc.x += v0.x; acc.y += v0.y; acc.z += v0.z; acc.w += v0.w;
        a1.x += v1.x; a1.y += v1.y; a1.z += v1.z; a1.w += v1.w;
        a2.x += v2.x; a2.y += v2.y; a2.z += v2.z; a2.w += v2.w;
        a3.x += v3.x; a3.y += v3.y; a3.z += v3.z; a3.w += v3.w;
    }
    for (; k < e; ++k) {
        float4 v = *(reinterpret_cast<const float4*>(x + (size_t)colidx[k] * DIM) + sub);
        acc.x += v.x; acc.y += v.y; acc.z += v.z; acc.w += v.w;
    }
    acc.x += (a1.x + a2.x) + a3.x;
    acc.y += (a1.y + a2.y) + a3.y;
    acc.z += (a1.z + a2.z) + a3.z;
    acc.w += (a1.w + a2.w) + a3.w;

    ushort4 pk;
    pk.x = f2bf(acc.x); pk.y = f2bf(acc.y); pk.z = f2bf(acc.z); pk.w = f2bf(acc.w);
    *reinterpret_cast<ushort4*>(aggb + (size_t)node * DIM + sub * 4) = pk;
}

// --- fused 2-layer MLP on MFMA ----------------------------------------------
__global__ __launch_bounds__(256) void mlp_mfma_kernel(
        const unsigned short* __restrict__ aggb,
        const unsigned short* __restrict__ W1p,
        const unsigned short* __restrict__ W2p,
        const float* __restrict__ b1,
        const float* __restrict__ b2,
        float* __restrict__ out) {
    __shared__ __align__(16) unsigned short hbuf[4][16][136];

    const int wid  = threadIdx.x >> 6;
    const int lane = threadIdx.x & 63;
    const int t = blockIdx.x * 4 + wid;
    if (t >= NN / 16) return;            // 625 tiles
    const int row0 = t * 16;
    const int r16  = lane & 15;
    const int kg   = lane >> 4;
    const int drow = kg * 4;

    bf16x8 af[4];
    #pragma unroll
    for (int kt = 0; kt < 4; ++kt)
        af[kt] = *reinterpret_cast<const bf16x8*>(
            aggb + (size_t)(row0 + r16) * DIM + kt * 32 + kg * 8);

    const f32x4 zero = {0.f, 0.f, 0.f, 0.f};
    f32x4 acc[8];
    #pragma unroll
    for (int nt = 0; nt < 8; ++nt) acc[nt] = zero;

    #pragma unroll
    for (int kt = 0; kt < 4; ++kt) {
        #pragma unroll
        for (int nt = 0; nt < 8; ++nt) {
            bf16x8 w = *reinterpret_cast<const bf16x8*>(
                W1p + ((nt * 4 + kt) * 64 + lane) * 8);
            acc[nt] = __builtin_amdgcn_mfma_f32_16x16x32_bf16(af[kt], w, acc[nt], 0, 0, 0);
        }
    }

    #pragma unroll
    for (int nt = 0; nt < 8; ++nt) {
        float bv = b1[nt * 16 + r16];
        #pragma unroll
        for (int r = 0; r < 4; ++r) {
            float h = fmaxf(acc[nt][r] + bv, 0.0f);
            hbuf[wid][drow + r][nt * 16 + r16] = f2bf(h);
        }
    }

    bf16x8 hf[4];
    #pragma unroll
    for (int kt = 0; kt < 4; ++kt)
        hf[kt] = *reinterpret_cast<const bf16x8*>(&hbuf[wid][r16][kt * 32 + kg * 8]);

    f32x4 acc2[8];
    #pragma unroll
    for (int nt = 0; nt < 8; ++nt) acc2[nt] = zero;

    #pragma unroll
    for (int kt = 0; kt < 4; ++kt) {
        #pragma unroll
        for (int nt = 0; nt < 8; ++nt) {
            bf16x8 w = *reinterpret_cast<const bf16x8*>(
                W2p + ((nt * 4 + kt) * 64 + lane) * 8);
            acc2[nt] = __builtin_amdgcn_mfma_f32_16x16x32_bf16(hf[kt], w, acc2[nt], 0, 0, 0);
        }
    }

    #pragma unroll
    for (int nt = 0; nt < 8; ++nt) {
        float bv = b2[nt * 16 + r16];
        #pragma unroll
        for (int r = 0; r < 4; ++r)
            out[(size_t)(row0 + drow + r) * DIM + nt * 16 + r16] = acc2[nt][r] + bv;
    }
}

// ===========================================================================
// FALLBACK PATH (round-2 proven kernels; ws >= 2,682,880 B)
// ===========================================================================
__global__ void fb_zero_kernel(int* __restrict__ p, int n) {
    int i = blockIdx.x * blockDim.x + threadIdx.x;
    if (i < n) p[i] = 0;
}
__global__ void fb_count_kernel(const int* __restrict__ ei, int* __restrict__ deg) {
    int e = blockIdx.x * blockDim.x + threadIdx.x;
    if (e < NE) atomicAdd(&deg[ei[2 * e]], 1);
}
__global__ void fb_fill_kernel(const int* __restrict__ ei, const int* __restrict__ rowptr,
                               int* __restrict__ fill, int* __restrict__ colidx) {
    int e = blockIdx.x * blockDim.x + threadIdx.x;
    if (e < NE) {
        int r = ei[2 * e], c = ei[2 * e + 1];
        colidx[rowptr[r] + atomicAdd(&fill[r], 1)] = c;
    }
}
__global__ __launch_bounds__(128) void fb_gather_kernel(const float* __restrict__ x,
                                                        const int* __restrict__ rowptr,
                                                        const int* __restrict__ colidx,
                                                        float* __restrict__ agg) {
    const int n = blockIdx.x, j = threadIdx.x;
    const int s = rowptr[n], e = rowptr[n + 1];
    float acc = x[(size_t)n * DIM + j];
    float a0 = 0.f, a1 = 0.f, a2 = 0.f, a3 = 0.f;
    int k = s;
    for (; k + 4 <= e; k += 4) {
        a0 += x[(size_t)colidx[k + 0] * DIM + j];
        a1 += x[(size_t)colidx[k + 1] * DIM + j];
        a2 += x[(size_t)colidx[k + 2] * DIM + j];
        a3 += x[(size_t)colidx[k + 3] * DIM + j];
    }
    for (; k < e; ++k) acc += x[(size_t)colidx[k] * DIM + j];
    agg[(size_t)n * DIM + j] = acc + (a0 + a1) + (a2 + a3);
}
__global__ __launch_bounds__(512) void fb_mlp_kernel(
        const float* __restrict__ agg,
        const float* __restrict__ W1, const float* __restrict__ b1,
        const float* __restrict__ W2, const float* __restrict__ b2,
        float* __restrict__ out) {
    __shared__ float w1s[DIM * DIM];
    __shared__ float w2s[DIM * DIM];
    __shared__ float b1s[DIM], b2s[DIM];
    __shared__ float as[4][DIM], hs[4][DIM];
    for (int i = threadIdx.x; i < DIM * DIM; i += blockDim.x) { w1s[i] = W1[i]; w2s[i] = W2[i]; }
    if (threadIdx.x < DIM) { b1s[threadIdx.x] = b1[threadIdx.x]; b2s[threadIdx.x] = b2[threadIdx.x]; }
    __syncthreads();
    const int r = threadIdx.x >> 7, j = threadIdx.x & 127;
    for (int base = blockIdx.x * 4; base < NN; base += gridDim.x * 4) {
        int rowid = base + r;
        as[r][j] = (rowid < NN) ? agg[(size_t)rowid * DIM + j] : 0.0f;
        __syncthreads();
        float acc = b1s[j];
        #pragma unroll 8
        for (int k = 0; k < DIM; ++k) acc = fmaf(as[r][k], w1s[k * DIM + j], acc);
        hs[r][j] = fmaxf(acc, 0.0f);
        __syncthreads();
        float acc2 = b2s[j];
        #pragma unroll 8
        for (int k = 0; k < DIM; ++k) acc2 = fmaf(hs[r][k], w2s[k * DIM + j], acc2);
        if (rowid < NN) out[(size_t)rowid * DIM + j] = acc2;
        __syncthreads();
    }
}

// ===========================================================================
extern "C" void kernel_launch(void* const* d_in, const int* in_sizes, int n_in,
                              void* d_out, int out_size, void* d_ws, size_t ws_size,
                              hipStream_t stream) {
    const float* x  = (const float*)d_in[0];
    const int*   ei = (const int*)d_in[1];
    const float* W1 = (const float*)d_in[2];
    const float* b1 = (const float*)d_in[3];
    const float* W2 = (const float*)d_in[4];
    const float* b2 = (const float*)d_in[5];
    float* out = (float*)d_out;

    if (ws_size >= WS_NEED) {
        char* ws = (char*)d_ws;
        int* deg8 = (int*)ws;                                  // -> repoff after repoff_kernel
        unsigned char* rank = (unsigned char*)(ws + OFF_RANK);
        int* deg    = (int*)(ws + OFF_DEG);
        unsigned short* aggb = (unsigned short*)ws;            // overlays deg8+rank+deg
        int* rowptr = (int*)(ws + OFF_ROWPTR);
        int* colidx = (int*)(ws + OFF_COLIDX);
        unsigned short* W1p = (unsigned short*)(ws + OFF_W1P);
        unsigned short* W2p = (unsigned short*)(ws + OFF_W2P);

        pack_zero_kernel<<<(32768 + NREP * ROWS_PAD + 255) / 256, 256, 0, stream>>>(
            W1, W2, W1p, W2p, deg8);
        count_rank_kernel<<<(NE + 255) / 256, 256, 0, stream>>>(ei, deg8, rank);
        reduce_deg_kernel<<<(NN + 255) / 256, 256, 0, stream>>>(deg8, deg);
        scan_kernel<<<1, 1024, 0, stream>>>(deg, rowptr);
        repoff_kernel<<<(NN + 255) / 256, 256, 0, stream>>>(deg8, rowptr);
        fill_rank_kernel<<<(NE + 255) / 256, 256, 0, stream>>>(ei, rank, deg8, colidx);
        gather_bf16_kernel<<<NN / 8, 256, 0, stream>>>(x, rowptr, colidx, aggb);
        mlp_mfma_kernel<<<(NN / 16 + 3) / 4, 256, 0, stream>>>(aggb, W1p, W2p, b1, b2, out);
    } else {
        int* wsI    = (int*)d_ws;
        int* deg    = wsI;
        int* fillc  = wsI + 10240;
        int* rowptr = wsI + 20480;
        int* colidx = wsI + 30720;
        const size_t csr_bytes = (size_t)(30720 + NE) * sizeof(int);
        const size_t agg_bytes = (size_t)NN * DIM * sizeof(float);
        float* agg = (ws_size >= csr_bytes + agg_bytes)
                         ? (float*)((char*)d_ws + csr_bytes) : out;

        fb_zero_kernel<<<(20480 + 255) / 256, 256, 0, stream>>>(deg, 20480);
        fb_count_kernel<<<(NE + 255) / 256, 256, 0, stream>>>(ei, deg);
        scan_kernel<<<1, 1024, 0, stream>>>(deg, rowptr);
        fb_fill_kernel<<<(NE + 255) / 256, 256, 0, stream>>>(ei, rowptr, fillc, colidx);
        fb_gather_kernel<<<NN, 128, 0, stream>>>(x, rowptr, colidx, agg);
        fb_mlp_kernel<<<256, 512, 0, stream>>>(agg, W1, b1, W2, b2, out);
    }
}

// Round 6
// 71.918 us; speedup vs baseline: 1.8143x; 1.1324x over previous
//
#include <hip/hip_runtime.h>

#define NN   10000
#define NE   640000
#define DIM  128
#define NREP 8
#define CAP  64        // slots per (row, replica); deg_max ~110, Binom(110,1/8) >64 ~ never
#define ROWS_PAD 10240

typedef __attribute__((ext_vector_type(8))) short bf16x8;
typedef __attribute__((ext_vector_type(8))) unsigned short u16x8;
typedef __attribute__((ext_vector_type(4))) float f32x4;

__device__ inline unsigned short f2bf(float f) {
    unsigned u = __builtin_bit_cast(unsigned, f);
    unsigned r = (u + 0x7fffu + ((u >> 16) & 1u)) >> 16;
    return (unsigned short)r;
}
__device__ inline float bf2f(unsigned short u) {
    return __builtin_bit_cast(float, (unsigned)u << 16);
}

// ===========================================================================
// PRIMARY ws layout (bytes), total 15,753,216:
//   cnt8  [8][10240] int            @ 0           (327,680)
//   bucket ushort[10000][8][64]     @ 327,680     (10,240,000)
//   xb    ushort[1,280,000]         @ 10,567,680  (2,560,000)   bf16 of x
//   aggb  ushort[1,280,000]         @ 13,127,680  (2,560,000)
//   W1p   ushort[16384]             @ 15,687,680  (32,768)  bf16 MFMA-frag order
//   W2p   ushort[16384]             @ 15,720,448  (32,768)
// ===========================================================================
#define OFF_BUCKET 327680
#define OFF_XB     10567680
#define OFF_AGGB   13127680
#define OFF_W1P    15687680
#define OFF_W2P    15720448
#define WS_NEED    15753216

// --- prep: pack W1/W2 (MFMA B-frag bf16), zero cnt8, convert x -> bf16 ------
// id ranges: [0,32768) weights | [32768,114688) zero cnt8 | [114688,274688) x
__global__ void prep_kernel(const float* __restrict__ W1,
                            const float* __restrict__ W2,
                            const float* __restrict__ x,
                            unsigned short* __restrict__ W1p,
                            unsigned short* __restrict__ W2p,
                            unsigned short* __restrict__ xb,
                            int* __restrict__ cnt8) {
    int id = blockIdx.x * 256 + threadIdx.x;
    if (id < 32768) {
        const float* W = (id < 16384) ? W1 : W2;
        unsigned short* Wp = (id < 16384) ? W1p : W2p;
        int f = id & 16383;
        int e = f & 7, lane = (f >> 3) & 63, kt = (f >> 9) & 3, nt = f >> 11;
        int kglob = kt * 32 + (lane >> 4) * 8 + e;
        int jglob = nt * 16 + (lane & 15);
        Wp[f] = f2bf(W[kglob * DIM + jglob]);
    } else if (id < 114688) {
        cnt8[id - 32768] = 0;
    } else if (id < 114688 + NN * DIM / 8) {
        int i = (id - 114688) * 8;
        float4 a = *reinterpret_cast<const float4*>(x + i);
        float4 b = *reinterpret_cast<const float4*>(x + i + 4);
        u16x8 pk;
        pk[0] = f2bf(a.x); pk[1] = f2bf(a.y); pk[2] = f2bf(a.z); pk[3] = f2bf(a.w);
        pk[4] = f2bf(b.x); pk[5] = f2bf(b.y); pk[6] = f2bf(b.z); pk[7] = f2bf(b.w);
        *reinterpret_cast<u16x8*>(xb + i) = pk;
    }
}

// --- single pass: bucket[row][rep][slot] = col ------------------------------
// rep = blockIdx&7 -> 8-way replicated counters, avg atomic chain ~8.
__global__ void fill_direct_kernel(const int* __restrict__ ei,
                                   int* __restrict__ cnt8,
                                   unsigned short* __restrict__ bucket) {
    int e = blockIdx.x * 256 + threadIdx.x;
    if (e < NE) {
        int2 rc = *reinterpret_cast<const int2*>(ei + 2 * e);
        int rep = blockIdx.x & (NREP - 1);
        int slot = atomicAdd(&cnt8[rep * ROWS_PAD + rc.x], 1);
        if (slot < CAP)
            bucket[(size_t)rc.x * (NREP * CAP) + rep * CAP + slot] = (unsigned short)rc.y;
    }
}

// --- gather from buckets: aggb[n,:] = bf16(x[n,:] + sum_neighbors x[c,:]) ---
// 16 lanes per node, 8 bf16 cols per lane, f32 accumulate, 4-deep ILP.
__global__ __launch_bounds__(256) void gather_bucket_kernel(
        const unsigned short* __restrict__ xb,
        const int* __restrict__ cnt8,
        const unsigned short* __restrict__ bucket,
        unsigned short* __restrict__ aggb) {
    const int node = blockIdx.x * 16 + (threadIdx.x >> 4);
    const int l    = threadIdx.x & 15;

    float acc[8];
    {
        u16x8 v = *reinterpret_cast<const u16x8*>(xb + (size_t)node * DIM + l * 8);
        #pragma unroll
        for (int j = 0; j < 8; ++j) acc[j] = bf2f(v[j]);
    }

    const unsigned short* brow = bucket + (size_t)node * (NREP * CAP);
    #pragma unroll
    for (int rep = 0; rep < NREP; ++rep) {
        int m = cnt8[rep * ROWS_PAD + node];
        m = (m > CAP) ? CAP : m;
        const unsigned short* seg = brow + rep * CAP;
        int k = 0;
        for (; k + 4 <= m; k += 4) {
            ushort4 c = *reinterpret_cast<const ushort4*>(seg + k);
            u16x8 v0 = *reinterpret_cast<const u16x8*>(xb + (size_t)c.x * DIM + l * 8);
            u16x8 v1 = *reinterpret_cast<const u16x8*>(xb + (size_t)c.y * DIM + l * 8);
            u16x8 v2 = *reinterpret_cast<const u16x8*>(xb + (size_t)c.z * DIM + l * 8);
            u16x8 v3 = *reinterpret_cast<const u16x8*>(xb + (size_t)c.w * DIM + l * 8);
            #pragma unroll
            for (int j = 0; j < 8; ++j)
                acc[j] += (bf2f(v0[j]) + bf2f(v1[j])) + (bf2f(v2[j]) + bf2f(v3[j]));
        }
        for (; k < m; ++k) {
            u16x8 v = *reinterpret_cast<const u16x8*>(xb + (size_t)seg[k] * DIM + l * 8);
            #pragma unroll
            for (int j = 0; j < 8; ++j) acc[j] += bf2f(v[j]);
        }
    }

    u16x8 pk;
    #pragma unroll
    for (int j = 0; j < 8; ++j) pk[j] = f2bf(acc[j]);
    *reinterpret_cast<u16x8*>(aggb + (size_t)node * DIM + l * 8) = pk;
}

// --- fused 2-layer MLP on MFMA (proven round-3/5 kernel) --------------------
__global__ __launch_bounds__(256) void mlp_mfma_kernel(
        const unsigned short* __restrict__ aggb,
        const unsigned short* __restrict__ W1p,
        const unsigned short* __restrict__ W2p,
        const float* __restrict__ b1,
        const float* __restrict__ b2,
        float* __restrict__ out) {
    __shared__ __align__(16) unsigned short hbuf[4][16][136];

    const int wid  = threadIdx.x >> 6;
    const int lane = threadIdx.x & 63;
    const int t = blockIdx.x * 4 + wid;
    if (t >= NN / 16) return;            // 625 tiles
    const int row0 = t * 16;
    const int r16  = lane & 15;
    const int kg   = lane >> 4;
    const int drow = kg * 4;

    bf16x8 af[4];
    #pragma unroll
    for (int kt = 0; kt < 4; ++kt)
        af[kt] = *reinterpret_cast<const bf16x8*>(
            aggb + (size_t)(row0 + r16) * DIM + kt * 32 + kg * 8);

    const f32x4 zero = {0.f, 0.f, 0.f, 0.f};
    f32x4 acc[8];
    #pragma unroll
    for (int nt = 0; nt < 8; ++nt) acc[nt] = zero;

    #pragma unroll
    for (int kt = 0; kt < 4; ++kt) {
        #pragma unroll
        for (int nt = 0; nt < 8; ++nt) {
            bf16x8 w = *reinterpret_cast<const bf16x8*>(
                W1p + ((nt * 4 + kt) * 64 + lane) * 8);
            acc[nt] = __builtin_amdgcn_mfma_f32_16x16x32_bf16(af[kt], w, acc[nt], 0, 0, 0);
        }
    }

    #pragma unroll
    for (int nt = 0; nt < 8; ++nt) {
        float bv = b1[nt * 16 + r16];
        #pragma unroll
        for (int r = 0; r < 4; ++r) {
            float h = fmaxf(acc[nt][r] + bv, 0.0f);
            hbuf[wid][drow + r][nt * 16 + r16] = f2bf(h);
        }
    }

    bf16x8 hf[4];
    #pragma unroll
    for (int kt = 0; kt < 4; ++kt)
        hf[kt] = *reinterpret_cast<const bf16x8*>(&hbuf[wid][r16][kt * 32 + kg * 8]);

    f32x4 acc2[8];
    #pragma unroll
    for (int nt = 0; nt < 8; ++nt) acc2[nt] = zero;

    #pragma unroll
    for (int kt = 0; kt < 4; ++kt) {
        #pragma unroll
        for (int nt = 0; nt < 8; ++nt) {
            bf16x8 w = *reinterpret_cast<const bf16x8*>(
                W2p + ((nt * 4 + kt) * 64 + lane) * 8);
            acc2[nt] = __builtin_amdgcn_mfma_f32_16x16x32_bf16(hf[kt], w, acc2[nt], 0, 0, 0);
        }
    }

    #pragma unroll
    for (int nt = 0; nt < 8; ++nt) {
        float bv = b2[nt * 16 + r16];
        #pragma unroll
        for (int r = 0; r < 4; ++r)
            out[(size_t)(row0 + drow + r) * DIM + nt * 16 + r16] = acc2[nt][r] + bv;
    }
}

// ===========================================================================
// FALLBACK PATH (round-2 proven f32 kernels; ws >= 2,682,880 B)
// ===========================================================================
__global__ void fb_zero_kernel(int* __restrict__ p, int n) {
    int i = blockIdx.x * blockDim.x + threadIdx.x;
    if (i < n) p[i] = 0;
}
__global__ void fb_count_kernel(const int* __restrict__ ei, int* __restrict__ deg) {
    int e = blockIdx.x * blockDim.x + threadIdx.x;
    if (e < NE) atomicAdd(&deg[ei[2 * e]], 1);
}
__global__ __launch_bounds__(1024) void fb_scan_kernel(const int* __restrict__ deg,
                                                       int* __restrict__ rowptr) {
    __shared__ int wtot[16];
    const int t = threadIdx.x;
    const int base = t * 10;
    int local[10];
    int s = 0;
    #pragma unroll
    for (int i = 0; i < 10; ++i) {
        int v = (base + i < NN) ? deg[base + i] : 0;
        local[i] = s;
        s += v;
    }
    const int mySum = s;
    #pragma unroll
    for (int off = 1; off < 64; off <<= 1) {
        int v = __shfl_up(s, (unsigned)off, 64);
        if ((t & 63) >= off) s += v;
    }
    if ((t & 63) == 63) wtot[t >> 6] = s;
    __syncthreads();
    if (t == 0) {
        int run = 0;
        #pragma unroll
        for (int i = 0; i < 16; ++i) { int v = wtot[i]; wtot[i] = run; run += v; }
    }
    __syncthreads();
    const int ex = wtot[t >> 6] + (s - mySum);
    #pragma unroll
    for (int i = 0; i < 10; ++i)
        if (base + i < NN) rowptr[base + i] = ex + local[i];
    if (t == 1023) rowptr[NN] = ex + mySum;
}
__global__ void fb_fill_kernel(const int* __restrict__ ei, const int* __restrict__ rowptr,
                               int* __restrict__ fill, int* __restrict__ colidx) {
    int e = blockIdx.x * blockDim.x + threadIdx.x;
    if (e < NE) {
        int r = ei[2 * e], c = ei[2 * e + 1];
        colidx[rowptr[r] + atomicAdd(&fill[r], 1)] = c;
    }
}
__global__ __launch_bounds__(128) void fb_gather_kernel(const float* __restrict__ x,
                                                        const int* __restrict__ rowptr,
                                                        const int* __restrict__ colidx,
                                                        float* __restrict__ agg) {
    const int n = blockIdx.x, j = threadIdx.x;
    const int s = rowptr[n], e = rowptr[n + 1];
    float acc = x[(size_t)n * DIM + j];
    float a0 = 0.f, a1 = 0.f, a2 = 0.f, a3 = 0.f;
    int k = s;
    for (; k + 4 <= e; k += 4) {
        a0 += x[(size_t)colidx[k + 0] * DIM + j];
        a1 += x[(size_t)colidx[k + 1] * DIM + j];
        a2 += x[(size_t)colidx[k + 2] * DIM + j];
        a3 += x[(size_t)colidx[k + 3] * DIM + j];
    }
    for (; k < e; ++k) acc += x[(size_t)colidx[k] * DIM + j];
    agg[(size_t)n * DIM + j] = acc + (a0 + a1) + (a2 + a3);
}
__global__ __launch_bounds__(512) void fb_mlp_kernel(
        const float* __restrict__ agg,
        const float* __restrict__ W1, const float* __restrict__ b1,
        const float* __restrict__ W2, const float* __restrict__ b2,
        float* __restrict__ out) {
    __shared__ float w1s[DIM * DIM];
    __shared__ float w2s[DIM * DIM];
    __shared__ float b1s[DIM], b2s[DIM];
    __shared__ float as[4][DIM], hs[4][DIM];
    for (int i = threadIdx.x; i < DIM * DIM; i += blockDim.x) { w1s[i] = W1[i]; w2s[i] = W2[i]; }
    if (threadIdx.x < DIM) { b1s[threadIdx.x] = b1[threadIdx.x]; b2s[threadIdx.x] = b2[threadIdx.x]; }
    __syncthreads();
    const int r = threadIdx.x >> 7, j = threadIdx.x & 127;
    for (int base = blockIdx.x * 4; base < NN; base += gridDim.x * 4) {
        int rowid = base + r;
        as[r][j] = (rowid < NN) ? agg[(size_t)rowid * DIM + j] : 0.0f;
        __syncthreads();
        float acc = b1s[j];
        #pragma unroll 8
        for (int k = 0; k < DIM; ++k) acc = fmaf(as[r][k], w1s[k * DIM + j], acc);
        hs[r][j] = fmaxf(acc, 0.0f);
        __syncthreads();
        float acc2 = b2s[j];
        #pragma unroll 8
        for (int k = 0; k < DIM; ++k) acc2 = fmaf(hs[r][k], w2s[k * DIM + j], acc2);
        if (rowid < NN) out[(size_t)rowid * DIM + j] = acc2;
        __syncthreads();
    }
}

// ===========================================================================
extern "C" void kernel_launch(void* const* d_in, const int* in_sizes, int n_in,
                              void* d_out, int out_size, void* d_ws, size_t ws_size,
                              hipStream_t stream) {
    const float* x  = (const float*)d_in[0];
    const int*   ei = (const int*)d_in[1];
    const float* W1 = (const float*)d_in[2];
    const float* b1 = (const float*)d_in[3];
    const float* W2 = (const float*)d_in[4];
    const float* b2 = (const float*)d_in[5];
    float* out = (float*)d_out;

    if (ws_size >= WS_NEED) {
        char* ws = (char*)d_ws;
        int* cnt8 = (int*)ws;
        unsigned short* bucket = (unsigned short*)(ws + OFF_BUCKET);
        unsigned short* xb     = (unsigned short*)(ws + OFF_XB);
        unsigned short* aggb   = (unsigned short*)(ws + OFF_AGGB);
        unsigned short* W1p    = (unsigned short*)(ws + OFF_W1P);
        unsigned short* W2p    = (unsigned short*)(ws + OFF_W2P);

        const int prep_threads = 114688 + NN * DIM / 8;   // 274,688
        prep_kernel<<<(prep_threads + 255) / 256, 256, 0, stream>>>(
            W1, W2, x, W1p, W2p, xb, cnt8);
        fill_direct_kernel<<<NE / 256, 256, 0, stream>>>(ei, cnt8, bucket);
        gather_bucket_kernel<<<NN / 16, 256, 0, stream>>>(xb, cnt8, bucket, aggb);
        mlp_mfma_kernel<<<(NN / 16 + 3) / 4, 256, 0, stream>>>(aggb, W1p, W2p, b1, b2, out);
    } else {
        int* wsI    = (int*)d_ws;
        int* deg    = wsI;
        int* fillc  = wsI + 10240;
        int* rowptr = wsI + 20480;
        int* colidx = wsI + 30720;
        const size_t csr_bytes = (size_t)(30720 + NE) * sizeof(int);
        const size_t agg_bytes = (size_t)NN * DIM * sizeof(float);
        float* agg = (ws_size >= csr_bytes + agg_bytes)
                         ? (float*)((char*)d_ws + csr_bytes) : out;

        fb_zero_kernel<<<(20480 + 255) / 256, 256, 0, stream>>>(deg, 20480);
        fb_count_kernel<<<(NE + 255) / 256, 256, 0, stream>>>(ei, deg);
        fb_scan_kernel<<<1, 1024, 0, stream>>>(deg, rowptr);
        fb_fill_kernel<<<(NE + 255) / 256, 256, 0, stream>>>(ei, rowptr, fillc, colidx);
        fb_gather_kernel<<<NN, 128, 0, stream>>>(x, rowptr, colidx, agg);
        fb_mlp_kernel<<<256, 512, 0, stream>>>(agg, W1, b1, W2, b2, out);
    }
}

// Round 7
// 68.710 us; speedup vs baseline: 1.8990x; 1.0467x over previous
//
#include <hip/hip_runtime.h>

#define NN   10000
#define NE   640000
#define DIM  128
#define NREP 8
#define CAP  64        // slots per (row, replica); deg~Binom(640K,1/10K)->mean 64 over 8 reps = 8/rep
#define ROWS_PAD 10240

typedef __attribute__((ext_vector_type(8))) short bf16x8;
typedef __attribute__((ext_vector_type(8))) unsigned short u16x8;
typedef __attribute__((ext_vector_type(4))) float f32x4;

__device__ inline unsigned short f2bf(float f) {
    unsigned u = __builtin_bit_cast(unsigned, f);
    unsigned r = (u + 0x7fffu + ((u >> 16) & 1u)) >> 16;
    return (unsigned short)r;
}
__device__ inline float bf2f(unsigned short u) {
    return __builtin_bit_cast(float, (unsigned)u << 16);
}

// ===========================================================================
// PRIMARY ws layout (bytes), total 13,193,216:
//   cnt8  [8][10240] int            @ 0           (327,680)
//   bucket ushort[10000][8][64]     @ 327,680     (10,240,000)
//   xb    ushort[1,280,000]         @ 10,567,680  (2,560,000)   bf16 of x
//   W1p   ushort[16384]             @ 13,127,680  (32,768)  bf16 MFMA-frag order
//   W2p   ushort[16384]             @ 13,160,448  (32,768)
// ===========================================================================
#define OFF_BUCKET 327680
#define OFF_XB     10567680
#define OFF_W1P    13127680
#define OFF_W2P    13160448
#define WS_NEED    13193216

// --- prep: pack W1/W2 (MFMA B-frag bf16), zero cnt8, convert x -> bf16 ------
// id ranges: [0,32768) weights | [32768,114688) zero cnt8 | [114688,274688) x
__global__ void prep_kernel(const float* __restrict__ W1,
                            const float* __restrict__ W2,
                            const float* __restrict__ x,
                            unsigned short* __restrict__ W1p,
                            unsigned short* __restrict__ W2p,
                            unsigned short* __restrict__ xb,
                            int* __restrict__ cnt8) {
    int id = blockIdx.x * 256 + threadIdx.x;
    if (id < 32768) {
        const float* W = (id < 16384) ? W1 : W2;
        unsigned short* Wp = (id < 16384) ? W1p : W2p;
        int f = id & 16383;
        int e = f & 7, lane = (f >> 3) & 63, kt = (f >> 9) & 3, nt = f >> 11;
        int kglob = kt * 32 + (lane >> 4) * 8 + e;
        int jglob = nt * 16 + (lane & 15);
        Wp[f] = f2bf(W[kglob * DIM + jglob]);
    } else if (id < 114688) {
        cnt8[id - 32768] = 0;
    } else if (id < 114688 + NN * DIM / 8) {
        int i = (id - 114688) * 8;
        float4 a = *reinterpret_cast<const float4*>(x + i);
        float4 b = *reinterpret_cast<const float4*>(x + i + 4);
        u16x8 pk;
        pk[0] = f2bf(a.x); pk[1] = f2bf(a.y); pk[2] = f2bf(a.z); pk[3] = f2bf(a.w);
        pk[4] = f2bf(b.x); pk[5] = f2bf(b.y); pk[6] = f2bf(b.z); pk[7] = f2bf(b.w);
        *reinterpret_cast<u16x8*>(xb + i) = pk;
    }
}

// --- single pass: bucket[row][rep][slot] = col ------------------------------
// rep = blockIdx&7 -> 8-way replicated counters, avg atomic chain ~8.
__global__ void fill_direct_kernel(const int* __restrict__ ei,
                                   int* __restrict__ cnt8,
                                   unsigned short* __restrict__ bucket) {
    int e = blockIdx.x * 256 + threadIdx.x;
    if (e < NE) {
        int2 rc = *reinterpret_cast<const int2*>(ei + 2 * e);
        int rep = blockIdx.x & (NREP - 1);
        int slot = atomicAdd(&cnt8[rep * ROWS_PAD + rc.x], 1);
        if (slot < CAP)
            bucket[(size_t)rc.x * (NREP * CAP) + rep * CAP + slot] = (unsigned short)rc.y;
    }
}

// --- fused gather + 2-layer MFMA MLP ----------------------------------------
// One 256-thread block per 16-node tile (625 blocks).
// Phase 1: gather tile rows from buckets -> LDS aggs (bf16), 16 lanes/node.
// Phase 2: 4 waves split the MLP by column-quadrant; h shared via LDS hbuf.
// A-frag (16x16x32): lane l elem e = A[l&15][kt*32+(l>>4)*8+e].
// D-frag: lane l reg r = D[(l>>4)*4+r][l&15].
__global__ __launch_bounds__(256) void gather_mlp_kernel(
        const unsigned short* __restrict__ xb,
        const int* __restrict__ cnt8,
        const unsigned short* __restrict__ bucket,
        const unsigned short* __restrict__ W1p,
        const unsigned short* __restrict__ W2p,
        const float* __restrict__ b1,
        const float* __restrict__ b2,
        float* __restrict__ out) {
    __shared__ __align__(16) unsigned short aggs[16][136];  // 272B row stride (16B-mult)
    __shared__ __align__(16) unsigned short hbuf[16][136];

    const int row0 = blockIdx.x * 16;

    // ---- phase 1: gather 16 nodes, 16 lanes each, 8 bf16 cols/lane ----
    {
        const int nl = threadIdx.x >> 4;   // 0..15: local node
        const int l  = threadIdx.x & 15;   // col group
        const int node = row0 + nl;

        float acc[8];
        {
            u16x8 v = *reinterpret_cast<const u16x8*>(xb + (size_t)node * DIM + l * 8);
            #pragma unroll
            for (int j = 0; j < 8; ++j) acc[j] = bf2f(v[j]);
        }
        const unsigned short* brow = bucket + (size_t)node * (NREP * CAP);
        #pragma unroll
        for (int rep = 0; rep < NREP; ++rep) {
            int m = cnt8[rep * ROWS_PAD + node];
            m = (m > CAP) ? CAP : m;
            const unsigned short* seg = brow + rep * CAP;
            int k = 0;
            for (; k + 4 <= m; k += 4) {
                ushort4 c = *reinterpret_cast<const ushort4*>(seg + k);
                u16x8 v0 = *reinterpret_cast<const u16x8*>(xb + (size_t)c.x * DIM + l * 8);
                u16x8 v1 = *reinterpret_cast<const u16x8*>(xb + (size_t)c.y * DIM + l * 8);
                u16x8 v2 = *reinterpret_cast<const u16x8*>(xb + (size_t)c.z * DIM + l * 8);
                u16x8 v3 = *reinterpret_cast<const u16x8*>(xb + (size_t)c.w * DIM + l * 8);
                #pragma unroll
                for (int j = 0; j < 8; ++j)
                    acc[j] += (bf2f(v0[j]) + bf2f(v1[j])) + (bf2f(v2[j]) + bf2f(v3[j]));
            }
            for (; k < m; ++k) {
                u16x8 v = *reinterpret_cast<const u16x8*>(xb + (size_t)seg[k] * DIM + l * 8);
                #pragma unroll
                for (int j = 0; j < 8; ++j) acc[j] += bf2f(v[j]);
            }
        }
        u16x8 pk;
        #pragma unroll
        for (int j = 0; j < 8; ++j) pk[j] = f2bf(acc[j]);
        *reinterpret_cast<u16x8*>(&aggs[nl][l * 8]) = pk;
    }
    __syncthreads();

    // ---- phase 2: MLP, wave w owns cols [32w, 32w+32) of both layers ----
    const int wid  = threadIdx.x >> 6;
    const int lane = threadIdx.x & 63;
    const int r16  = lane & 15;
    const int kg   = lane >> 4;
    const int drow = kg * 4;

    bf16x8 af[4];
    #pragma unroll
    for (int kt = 0; kt < 4; ++kt)
        af[kt] = *reinterpret_cast<const bf16x8*>(&aggs[r16][kt * 32 + kg * 8]);

    const f32x4 zero = {0.f, 0.f, 0.f, 0.f};
    f32x4 acc1[2] = {zero, zero};
    #pragma unroll
    for (int kt = 0; kt < 4; ++kt) {
        #pragma unroll
        for (int q = 0; q < 2; ++q) {
            int nt = wid * 2 + q;
            bf16x8 w = *reinterpret_cast<const bf16x8*>(
                W1p + ((nt * 4 + kt) * 64 + lane) * 8);
            acc1[q] = __builtin_amdgcn_mfma_f32_16x16x32_bf16(af[kt], w, acc1[q], 0, 0, 0);
        }
    }
    #pragma unroll
    for (int q = 0; q < 2; ++q) {
        int nt = wid * 2 + q;
        float bv = b1[nt * 16 + r16];
        #pragma unroll
        for (int r = 0; r < 4; ++r) {
            float h = fmaxf(acc1[q][r] + bv, 0.0f);
            hbuf[drow + r][nt * 16 + r16] = f2bf(h);
        }
    }
    __syncthreads();

    bf16x8 hf[4];
    #pragma unroll
    for (int kt = 0; kt < 4; ++kt)
        hf[kt] = *reinterpret_cast<const bf16x8*>(&hbuf[r16][kt * 32 + kg * 8]);

    f32x4 acc2[2] = {zero, zero};
    #pragma unroll
    for (int kt = 0; kt < 4; ++kt) {
        #pragma unroll
        for (int q = 0; q < 2; ++q) {
            int nt = wid * 2 + q;
            bf16x8 w = *reinterpret_cast<const bf16x8*>(
                W2p + ((nt * 4 + kt) * 64 + lane) * 8);
            acc2[q] = __builtin_amdgcn_mfma_f32_16x16x32_bf16(hf[kt], w, acc2[q], 0, 0, 0);
        }
    }
    #pragma unroll
    for (int q = 0; q < 2; ++q) {
        int nt = wid * 2 + q;
        float bv = b2[nt * 16 + r16];
        #pragma unroll
        for (int r = 0; r < 4; ++r)
            out[(size_t)(row0 + drow + r) * DIM + nt * 16 + r16] = acc2[q][r] + bv;
    }
}

// ===========================================================================
// FALLBACK PATH (round-2 proven f32 kernels; ws >= 2,682,880 B)
// ===========================================================================
__global__ void fb_zero_kernel(int* __restrict__ p, int n) {
    int i = blockIdx.x * blockDim.x + threadIdx.x;
    if (i < n) p[i] = 0;
}
__global__ void fb_count_kernel(const int* __restrict__ ei, int* __restrict__ deg) {
    int e = blockIdx.x * blockDim.x + threadIdx.x;
    if (e < NE) atomicAdd(&deg[ei[2 * e]], 1);
}
__global__ __launch_bounds__(1024) void fb_scan_kernel(const int* __restrict__ deg,
                                                       int* __restrict__ rowptr) {
    __shared__ int wtot[16];
    const int t = threadIdx.x;
    const int base = t * 10;
    int local[10];
    int s = 0;
    #pragma unroll
    for (int i = 0; i < 10; ++i) {
        int v = (base + i < NN) ? deg[base + i] : 0;
        local[i] = s;
        s += v;
    }
    const int mySum = s;
    #pragma unroll
    for (int off = 1; off < 64; off <<= 1) {
        int v = __shfl_up(s, (unsigned)off, 64);
        if ((t & 63) >= off) s += v;
    }
    if ((t & 63) == 63) wtot[t >> 6] = s;
    __syncthreads();
    if (t == 0) {
        int run = 0;
        #pragma unroll
        for (int i = 0; i < 16; ++i) { int v = wtot[i]; wtot[i] = run; run += v; }
    }
    __syncthreads();
    const int ex = wtot[t >> 6] + (s - mySum);
    #pragma unroll
    for (int i = 0; i < 10; ++i)
        if (base + i < NN) rowptr[base + i] = ex + local[i];
    if (t == 1023) rowptr[NN] = ex + mySum;
}
__global__ void fb_fill_kernel(const int* __restrict__ ei, const int* __restrict__ rowptr,
                               int* __restrict__ fill, int* __restrict__ colidx) {
    int e = blockIdx.x * blockDim.x + threadIdx.x;
    if (e < NE) {
        int r = ei[2 * e], c = ei[2 * e + 1];
        colidx[rowptr[r] + atomicAdd(&fill[r], 1)] = c;
    }
}
__global__ __launch_bounds__(128) void fb_gather_kernel(const float* __restrict__ x,
                                                        const int* __restrict__ rowptr,
                                                        const int* __restrict__ colidx,
                                                        float* __restrict__ agg) {
    const int n = blockIdx.x, j = threadIdx.x;
    const int s = rowptr[n], e = rowptr[n + 1];
    float acc = x[(size_t)n * DIM + j];
    float a0 = 0.f, a1 = 0.f, a2 = 0.f, a3 = 0.f;
    int k = s;
    for (; k + 4 <= e; k += 4) {
        a0 += x[(size_t)colidx[k + 0] * DIM + j];
        a1 += x[(size_t)colidx[k + 1] * DIM + j];
        a2 += x[(size_t)colidx[k + 2] * DIM + j];
        a3 += x[(size_t)colidx[k + 3] * DIM + j];
    }
    for (; k < e; ++k) acc += x[(size_t)colidx[k] * DIM + j];
    agg[(size_t)n * DIM + j] = acc + (a0 + a1) + (a2 + a3);
}
__global__ __launch_bounds__(512) void fb_mlp_kernel(
        const float* __restrict__ agg,
        const float* __restrict__ W1, const float* __restrict__ b1,
        const float* __restrict__ W2, const float* __restrict__ b2,
        float* __restrict__ out) {
    __shared__ float w1s[DIM * DIM];
    __shared__ float w2s[DIM * DIM];
    __shared__ float b1s[DIM], b2s[DIM];
    __shared__ float as[4][DIM], hs[4][DIM];
    for (int i = threadIdx.x; i < DIM * DIM; i += blockDim.x) { w1s[i] = W1[i]; w2s[i] = W2[i]; }
    if (threadIdx.x < DIM) { b1s[threadIdx.x] = b1[threadIdx.x]; b2s[threadIdx.x] = b2[threadIdx.x]; }
    __syncthreads();
    const int r = threadIdx.x >> 7, j = threadIdx.x & 127;
    for (int base = blockIdx.x * 4; base < NN; base += gridDim.x * 4) {
        int rowid = base + r;
        as[r][j] = (rowid < NN) ? agg[(size_t)rowid * DIM + j] : 0.0f;
        __syncthreads();
        float acc = b1s[j];
        #pragma unroll 8
        for (int k = 0; k < DIM; ++k) acc = fmaf(as[r][k], w1s[k * DIM + j], acc);
        hs[r][j] = fmaxf(acc, 0.0f);
        __syncthreads();
        float acc2 = b2s[j];
        #pragma unroll 8
        for (int k = 0; k < DIM; ++k) acc2 = fmaf(hs[r][k], w2s[k * DIM + j], acc2);
        if (rowid < NN) out[(size_t)rowid * DIM + j] = acc2;
        __syncthreads();
    }
}

// ===========================================================================
extern "C" void kernel_launch(void* const* d_in, const int* in_sizes, int n_in,
                              void* d_out, int out_size, void* d_ws, size_t ws_size,
                              hipStream_t stream) {
    const float* x  = (const float*)d_in[0];
    const int*   ei = (const int*)d_in[1];
    const float* W1 = (const float*)d_in[2];
    const float* b1 = (const float*)d_in[3];
    const float* W2 = (const float*)d_in[4];
    const float* b2 = (const float*)d_in[5];
    float* out = (float*)d_out;

    if (ws_size >= WS_NEED) {
        char* ws = (char*)d_ws;
        int* cnt8 = (int*)ws;
        unsigned short* bucket = (unsigned short*)(ws + OFF_BUCKET);
        unsigned short* xb     = (unsigned short*)(ws + OFF_XB);
        unsigned short* W1p    = (unsigned short*)(ws + OFF_W1P);
        unsigned short* W2p    = (unsigned short*)(ws + OFF_W2P);

        const int prep_threads = 114688 + NN * DIM / 8;   // 274,688
        prep_kernel<<<(prep_threads + 255) / 256, 256, 0, stream>>>(
            W1, W2, x, W1p, W2p, xb, cnt8);
        fill_direct_kernel<<<NE / 256, 256, 0, stream>>>(ei, cnt8, bucket);
        gather_mlp_kernel<<<NN / 16, 256, 0, stream>>>(
            xb, cnt8, bucket, W1p, W2p, b1, b2, out);
    } else {
        int* wsI    = (int*)d_ws;
        int* deg    = wsI;
        int* fillc  = wsI + 10240;
        int* rowptr = wsI + 20480;
        int* colidx = wsI + 30720;
        const size_t csr_bytes = (size_t)(30720 + NE) * sizeof(int);
        const size_t agg_bytes = (size_t)NN * DIM * sizeof(float);
        float* agg = (ws_size >= csr_bytes + agg_bytes)
                         ? (float*)((char*)d_ws + csr_bytes) : out;

        fb_zero_kernel<<<(20480 + 255) / 256, 256, 0, stream>>>(deg, 20480);
        fb_count_kernel<<<(NE + 255) / 256, 256, 0, stream>>>(ei, deg);
        fb_scan_kernel<<<1, 1024, 0, stream>>>(deg, rowptr);
        fb_fill_kernel<<<(NE + 255) / 256, 256, 0, stream>>>(ei, rowptr, fillc, colidx);
        fb_gather_kernel<<<NN, 128, 0, stream>>>(x, rowptr, colidx, agg);
        fb_mlp_kernel<<<256, 512, 0, stream>>>(agg, W1, b1, W2, b2, out);
    }
}